// Round 5
// baseline (2730.920 us; speedup 1.0000x reference)
//
#include <hip/hip_runtime.h>

// LSTM: I=H=1024, B=64, S=512.
//   pack_wT:    transpose+convert 8 weight mats -> WiT[4096][1024], WhT[4096][1024] bf16
//   pack_misc:  bias[4096] = b_i*+b_h*; zero tagged h ping-pong buffers (u32)
//   x2bf:       x fp32 -> bf16 (so gemm can use global_load_lds on both operands)
//   gemm_xproj: x_proj bf16 gate-interleaved [b*512+t][h][gate]; direct-to-LDS staging
//   lstm_scan:  persistent, 256 blocks (4 groups x 64 slices), 512 steps.
//               R5: tag-in-data h exchange — h published as u32 (bf16<<16)|step_tag,
//               single WT store/thread (no drain/barrier/flag); consumers do a cheap
//               sampled poll then a tag-validated 64KB bulk read. 2 MALL RTTs/step.
// Workspace: 352,862,208 B (guarded; ws_size is 512MiB per harness poison evidence).

typedef __bf16 bf16x8 __attribute__((ext_vector_type(8)));
typedef float f32x4 __attribute__((ext_vector_type(4)));
typedef unsigned int uint4v __attribute__((ext_vector_type(4)));

__device__ __forceinline__ unsigned short f2bf(float f) {
    unsigned int u = __float_as_uint(f);
    u = (u + 0x7FFFu + ((u >> 16) & 1u)) >> 16;
    return (unsigned short)u;
}
__device__ __forceinline__ float bf2f(unsigned short u) {
    return __uint_as_float((unsigned int)u << 16);
}

// ---------------------------------------------------------------------------
// Pack weights: out[n][k] = w[k][n&1023] for gate n>>10, bf16. 64x64 LDS transpose.
__global__ __launch_bounds__(256) void pack_wT(
    const float* __restrict__ w0, const float* __restrict__ w1,
    const float* __restrict__ w2, const float* __restrict__ w3,
    const float* __restrict__ w4, const float* __restrict__ w5,
    const float* __restrict__ w6, const float* __restrict__ w7,
    unsigned short* __restrict__ wiT, unsigned short* __restrict__ whT)
{
    __shared__ float tl[64][65];
    int bid = blockIdx.x;
    int mi = bid >> 8;          // 0..3 = Wi gates i,f,g,o; 4..7 = Wh
    int tile = bid & 255;
    int tk = tile >> 4, tj = tile & 15;
    const float* w;
    int gate = mi & 3;
    if (mi < 4) w = (gate == 0) ? w0 : (gate == 1) ? w1 : (gate == 2) ? w2 : w3;
    else        w = (gate == 0) ? w4 : (gate == 1) ? w5 : (gate == 2) ? w6 : w7;
    unsigned short* out = (mi < 4) ? wiT : whT;
    int tx = threadIdx.x & 63, ty = threadIdx.x >> 6;
    #pragma unroll
    for (int i = 0; i < 16; i++) {
        int k = i * 4 + ty;
        tl[k][tx] = w[(long)(tk * 64 + k) * 1024 + tj * 64 + tx];
    }
    __syncthreads();
    #pragma unroll
    for (int i = 0; i < 16; i++) {
        int j = i * 4 + ty;
        out[(long)(gate * 1024 + tj * 64 + j) * 1024 + tk * 64 + tx] = f2bf(tl[tx][j]);
    }
}

// ---------------------------------------------------------------------------
__global__ __launch_bounds__(256) void pack_misc(
    const float* __restrict__ bi0, const float* __restrict__ bh0,
    const float* __restrict__ bi1, const float* __restrict__ bh1,
    const float* __restrict__ bi2, const float* __restrict__ bh2,
    const float* __restrict__ bi3, const float* __restrict__ bh3,
    float* __restrict__ bias, unsigned int* __restrict__ hbuf_u)
{
    int idx = blockIdx.x * 256 + threadIdx.x;   // grid 512x256 = 131072
    hbuf_u[idx] = 0u;                            // tags=0, h=0 (both parities)
    if (idx < 4096) {
        int g = idx >> 10, j = idx & 1023;
        const float* bi = (g == 0) ? bi0 : (g == 1) ? bi1 : (g == 2) ? bi2 : bi3;
        const float* bh = (g == 0) ? bh0 : (g == 1) ? bh1 : (g == 2) ? bh2 : bh3;
        bias[idx] = bi[j] + bh[j];
    }
}

// ---------------------------------------------------------------------------
__global__ __launch_bounds__(256) void x2bf(const float* __restrict__ x,
                                            unsigned short* __restrict__ xbf)
{
    long i = ((long)blockIdx.x * 256 + threadIdx.x) * 8;   // grid 16384
    float4 a = *(const float4*)&x[i];
    float4 b = *(const float4*)&x[i + 4];
    uint4 v;
    v.x = (unsigned int)f2bf(a.x) | ((unsigned int)f2bf(a.y) << 16);
    v.y = (unsigned int)f2bf(a.z) | ((unsigned int)f2bf(a.w) << 16);
    v.z = (unsigned int)f2bf(b.x) | ((unsigned int)f2bf(b.y) << 16);
    v.w = (unsigned int)f2bf(b.z) | ((unsigned int)f2bf(b.w) << 16);
    *(uint4*)&xbf[i] = v;
}

// ---------------------------------------------------------------------------
// x_proj GEMM: xbf[32768][1024] @ Wi[1024][4096] -> xp[m][h][gate] bf16.
// 128x128 tile, BK=64. Staging via global_load_lds width=16 (both operands),
// XOR-swizzled chunk order (c_lds = c_g ^ (row&7)) since padding is forbidden.
__global__ __launch_bounds__(256, 2) void gemm_xproj(
    const unsigned short* __restrict__ xbf, const unsigned short* __restrict__ wiT,
    unsigned short* __restrict__ xp)
{
    __shared__ unsigned short sA[128 * 64];   // [row][8 chunks of 8 bf16], swizzled
    __shared__ unsigned short sB[128 * 64];
    int bid = blockIdx.x;
    int mt = bid >> 5, nt = bid & 31;
    long m0 = (long)mt * 128;
    int n0 = nt * 128;
    int tid = threadIdx.x;
    int lane = tid & 63, wv = tid >> 6;
    int quad = lane >> 4, l15 = lane & 15;
    int wm = wv & 1, wn = wv >> 1;

    f32x4 acc[4][4];
    #pragma unroll
    for (int a = 0; a < 4; a++)
        #pragma unroll
        for (int b = 0; b < 4; b++)
            acc[a][b] = (f32x4){0.f, 0.f, 0.f, 0.f};

    for (int kb = 0; kb < 16; kb++) {
        int k0 = kb * 64;
        // 1024 chunks of 16B per operand; each wave: 4 issues x 64 lanes.
        // lds chunk L = wv*256 + j*64 + lane holds global chunk (row, csrc),
        // row = L>>3, csrc = (lane&7) ^ ((lane>>3)&7).
        #pragma unroll
        for (int j = 0; j < 4; j++) {
            int Lb = wv * 256 + j * 64;                 // wave-uniform lds base chunk
            int row = (Lb >> 3) + (lane >> 3);
            int csrc = (lane & 7) ^ ((lane >> 3) & 7);
            const unsigned short* gA = xbf + (m0 + row) * 1024 + k0 + csrc * 8;
            __builtin_amdgcn_global_load_lds(
                (const __attribute__((address_space(1))) unsigned int*)gA,
                (__attribute__((address_space(3))) unsigned int*)&sA[Lb * 8],
                16, 0, 0);
            const unsigned short* gB = wiT + (long)(n0 + row) * 1024 + k0 + csrc * 8;
            __builtin_amdgcn_global_load_lds(
                (const __attribute__((address_space(1))) unsigned int*)gB,
                (__attribute__((address_space(3))) unsigned int*)&sB[Lb * 8],
                16, 0, 0);
        }
        __syncthreads();
        #pragma unroll
        for (int ks = 0; ks < 2; ks++) {
            bf16x8 af[4], bfr[4];
            #pragma unroll
            for (int mi2 = 0; mi2 < 4; mi2++) {
                int r = wm * 64 + mi2 * 16 + l15;
                af[mi2] = *(const bf16x8*)&sA[r * 64 + ((ks * 4 + quad) ^ (r & 7)) * 8];
            }
            #pragma unroll
            for (int ni = 0; ni < 4; ni++) {
                int r = wn * 64 + ni * 16 + l15;
                bfr[ni] = *(const bf16x8*)&sB[r * 64 + ((ks * 4 + quad) ^ (r & 7)) * 8];
            }
            #pragma unroll
            for (int mi2 = 0; mi2 < 4; mi2++)
                #pragma unroll
                for (int ni = 0; ni < 4; ni++)
                    acc[mi2][ni] = __builtin_amdgcn_mfma_f32_16x16x32_bf16(
                        af[mi2], bfr[ni], acc[mi2][ni], 0, 0, 0);
        }
        __syncthreads();
    }
    // epilogue: C rows = quad*4+r, cols = l15; gate-interleave scatter xp[m][h][gate]
    #pragma unroll
    for (int mi2 = 0; mi2 < 4; mi2++)
        #pragma unroll
        for (int ni = 0; ni < 4; ni++)
            #pragma unroll
            for (int r = 0; r < 4; r++) {
                long row = m0 + wm * 64 + mi2 * 16 + quad * 4 + r;
                int col = n0 + wn * 64 + ni * 16 + l15;
                int h = col & 1023, gate = col >> 10;
                xp[row * 4096 + h * 4 + gate] = f2bf(acc[mi2][ni][r]);
            }
}

// ---------------------------------------------------------------------------
// Persistent LSTM scan. 256 blocks x 256 threads.
// group g = bid/64 (batch rows 16g..16g+15), slice s = bid%64 (h cols 16s..16s+15).
// h exchange: u32 word = (bf16(h)<<16) | ((t+1)&0xFFFF), one relaxed WT store per
// thread, no producer barrier. Consumers: sampled poll then tag-validated bulk read.
__global__ __launch_bounds__(256, 1) void lstm_scan(
    const unsigned short* __restrict__ xp, const unsigned short* __restrict__ whT,
    const float* __restrict__ bias, unsigned int* __restrict__ hbuf,
    float* __restrict__ out)
{
    __shared__ unsigned short hl[16 * 1032];  // h tile [16][1024] bf16, stride 1032
    __shared__ float xch[4][16][16];          // gate exchange

    int bid = blockIdx.x;
    int g = bid >> 6, s = bid & 63;
    int tid = threadIdx.x;
    int lane = tid & 63, wv = tid >> 6;
    int quad = lane >> 4, l15 = lane & 15;

    // preload Wh fragments: B[k=kk*32+quad*8+j][n=l15] from WhT row (gate,col)
    bf16x8 bfrag[32];
    {
        const unsigned short* bp = whT + (long)(wv * 1024 + s * 16 + l15) * 1024 + quad * 8;
        #pragma unroll
        for (int kk = 0; kk < 32; kk++)
            bfrag[kk] = *(const bf16x8*)(bp + kk * 32);
    }

    int row = tid >> 4, col = tid & 15;       // elementwise ownership
    float b4[4];
    #pragma unroll
    for (int gg = 0; gg < 4; gg++) b4[gg] = bias[gg * 1024 + s * 16 + col];

    float c = 0.f;
    unsigned int* hbu0 = hbuf + g * 16 * 1024;                  // parity 0, u32[16][1024]
    unsigned int* hbu1 = hbuf + 4 * 16 * 1024 + g * 16 * 1024;  // parity 1

    for (int t = 0; t < 512; t++) {
        // x_proj prefetch: one 8B load = all 4 gates (hidden behind the poll)
        const unsigned short* xr = xp + ((long)(g * 16 + row) * 512 + t) * 4096
                                      + (s * 16 + col) * 4;
        uint2 xg = *(const uint2*)xr;

        unsigned int expect = (unsigned int)t & 0xFFFFu;
        const unsigned int* hsrc = (t & 1) ? hbu1 : hbu0;

        // cheap sampled poll: lane's sample covers slice (tid&63), row (tid>>6).
        // 256B per WG per poll round — no MALL thrashing while waiting.
        {
            const unsigned int* sp = hsrc + (tid >> 6) * 1024 + (tid & 63) * 16;
            while (true) {
                unsigned int w;
                asm volatile("global_load_dword %0, %1, off sc0 sc1\n\ts_waitcnt vmcnt(0)"
                             : "=v"(w) : "v"(sp) : "memory");
                if (__all((int)((w & 0xFFFFu) == expect))) break;
                __builtin_amdgcn_s_sleep(1);
            }
        }

        // bulk read 64KB tagged h, per-chunk validation (retries hit stragglers only)
        uint4v hv[16];
        unsigned int pend = 0xFFFFu;
        while (pend) {
            #pragma unroll
            for (int i = 0; i < 16; i++)
                if (pend & (1u << i)) {
                    const void* p = (const char*)hsrc + (tid + i * 256) * 16;
                    asm volatile("global_load_dwordx4 %0, %1, off sc0 sc1"
                                 : "=v"(hv[i]) : "v"(p) : "memory");
                }
            asm volatile("s_waitcnt vmcnt(0)" ::: "memory");
            #pragma unroll
            for (int i = 0; i < 16; i++)
                if (pend & (1u << i)) {
                    if (((hv[i].x & 0xFFFFu) == expect) && ((hv[i].y & 0xFFFFu) == expect) &&
                        ((hv[i].z & 0xFFFFu) == expect) && ((hv[i].w & 0xFFFFu) == expect))
                        pend &= ~(1u << i);
                }
        }
        // strip tags, pack bf16 pairs, store to LDS
        #pragma unroll
        for (int i = 0; i < 16; i++) {
            int ch = tid + i * 256;
            int r2 = ch >> 8, off = ch & 255;
            uint2 pk;
            pk.x = (hv[i].x >> 16) | (hv[i].y & 0xFFFF0000u);
            pk.y = (hv[i].z >> 16) | (hv[i].w & 0xFFFF0000u);
            *(uint2*)&hl[r2 * 1032 + off * 4] = pk;
        }
        __syncthreads();

        // gate tile for this wave: 16x16, K=1024
        f32x4 acc = {0.f, 0.f, 0.f, 0.f};
        #pragma unroll
        for (int kk = 0; kk < 32; kk++) {
            bf16x8 af = *(const bf16x8*)&hl[l15 * 1032 + kk * 32 + quad * 8];
            acc = __builtin_amdgcn_mfma_f32_16x16x32_bf16(af, bfrag[kk], acc, 0, 0, 0);
        }
        #pragma unroll
        for (int r = 0; r < 4; r++)
            xch[wv][quad * 4 + r][l15] = acc[r];
        __syncthreads();

        // elementwise LSTM cell
        float xpi = bf2f((unsigned short)(xg.x & 0xFFFF));
        float xpf = bf2f((unsigned short)(xg.x >> 16));
        float xpg = bf2f((unsigned short)(xg.y & 0xFFFF));
        float xpo = bf2f((unsigned short)(xg.y >> 16));
        float gi = xch[0][row][col] + xpi + b4[0];
        float gf = xch[1][row][col] + xpf + b4[1];
        float gg_ = xch[2][row][col] + xpg + b4[2];
        float go = xch[3][row][col] + xpo + b4[3];
        float iv = 1.f / (1.f + __expf(-gi));
        float fv = 1.f / (1.f + __expf(-gf));
        float gv = 1.f - 2.f / (__expf(2.f * gg_) + 1.f);   // tanh
        float ov = 1.f / (1.f + __expf(-go));
        c = c * fv + iv * gv;
        float h = ov * (1.f - 2.f / (__expf(2.f * c) + 1.f));

        if (t == 511) {
            out[(g * 16 + row) * 1024 + s * 16 + col] = h;
            out[65536 + (g * 16 + row) * 1024 + s * 16 + col] = c;
        } else {
            // publish h+tag in ONE dword: no drain, no barrier, no flag.
            unsigned int word = ((unsigned int)f2bf(h) << 16)
                              | ((unsigned int)(t + 1) & 0xFFFFu);
            unsigned int* hdst = ((t & 1) ? hbu0 : hbu1) + row * 1024 + s * 16 + col;
            __hip_atomic_store(hdst, word, __ATOMIC_RELAXED, __HIP_MEMORY_SCOPE_AGENT);
        }
    }
}

// ---------------------------------------------------------------------------
extern "C" void kernel_launch(void* const* d_in, const int* in_sizes, int n_in,
                              void* d_out, int out_size, void* d_ws, size_t ws_size,
                              hipStream_t stream)
{
    const float* x    = (const float*)d_in[0];
    const float* w_ii = (const float*)d_in[1];
    const float* b_ii = (const float*)d_in[2];
    const float* w_hi = (const float*)d_in[3];
    const float* b_hi = (const float*)d_in[4];
    const float* w_if = (const float*)d_in[5];
    const float* b_if = (const float*)d_in[6];
    const float* w_hf = (const float*)d_in[7];
    const float* b_hf = (const float*)d_in[8];
    const float* w_ig = (const float*)d_in[9];
    const float* b_ig = (const float*)d_in[10];
    const float* w_hg = (const float*)d_in[11];
    const float* b_hg = (const float*)d_in[12];
    const float* w_io = (const float*)d_in[13];
    const float* b_io = (const float*)d_in[14];
    const float* w_ho = (const float*)d_in[15];
    const float* b_ho = (const float*)d_in[16];

    // Workspace layout. Total = 352,862,208 B (< 512 MiB).
    const size_t OFF_XPJ  = 0;                       // 268,435,456
    const size_t OFF_XBF  = 268435456;               //  67,108,864
    const size_t OFF_WIT  = 335544320;               //   8,388,608
    const size_t OFF_WHT  = 343932928;               //   8,388,608
    const size_t OFF_BIAS = 352321536;               //      16,384
    const size_t OFF_HBUF = 352337920;               //     524,288
    const size_t NEEDED   = 352862208;
    if (ws_size < NEEDED) return;

    char* ws = (char*)d_ws;
    unsigned short* xpj  = (unsigned short*)(ws + OFF_XPJ);
    unsigned short* xbf  = (unsigned short*)(ws + OFF_XBF);
    unsigned short* wiT  = (unsigned short*)(ws + OFF_WIT);
    unsigned short* whT  = (unsigned short*)(ws + OFF_WHT);
    float*          bias = (float*)(ws + OFF_BIAS);
    unsigned int*   hbuf = (unsigned int*)(ws + OFF_HBUF);

    pack_wT<<<2048, 256, 0, stream>>>(w_ii, w_if, w_ig, w_io,
                                      w_hi, w_hf, w_hg, w_ho, wiT, whT);
    pack_misc<<<512, 256, 0, stream>>>(b_ii, b_hi, b_if, b_hf, b_ig, b_hg, b_io, b_ho,
                                       bias, hbuf);
    x2bf<<<16384, 256, 0, stream>>>(x, xbf);
    gemm_xproj<<<8192, 256, 0, stream>>>(xbf, wiT, xpj);
    lstm_scan<<<256, 256, 0, stream>>>(xpj, whT, bias, hbuf, (float*)d_out);
}

// Round 6
// 2415.511 us; speedup vs baseline: 1.1306x; 1.1306x over previous
//
#include <hip/hip_runtime.h>

// LSTM: I=H=1024, B=64, S=512.
//   pack_wT:    transpose+convert 8 weight mats -> WiT[4096][1024], WhT[4096][1024] bf16
//   pack_misc:  bias[4096]; zero bf16 h ping-pong buffers + 256 epoch flags
//   x2bf:       x fp32 -> bf16
//   gemm_xproj: x_proj bf16 gate-interleaved [b*512+t][h][gate]; global_load_lds staging
//   lstm_scan:  persistent, 256 blocks (4 groups x 64 slices), 512 steps.
//               R6: R4 flag-barrier skeleton (R5 tag-in-data regressed: 2x bytes +
//               retry storms) + split-half poll/stage/MFMA pipeline with raw s_barrier
//               (lgkmcnt-only) so half-2 staging flies under half-1 MFMA.
// Workspace: 352,602,112 B (guarded).

typedef __bf16 bf16x8 __attribute__((ext_vector_type(8)));
typedef float f32x4 __attribute__((ext_vector_type(4)));
typedef unsigned int uint4v __attribute__((ext_vector_type(4)));

__device__ __forceinline__ unsigned short f2bf(float f) {
    unsigned int u = __float_as_uint(f);
    u = (u + 0x7FFFu + ((u >> 16) & 1u)) >> 16;
    return (unsigned short)u;
}
__device__ __forceinline__ float bf2f(unsigned short u) {
    return __uint_as_float((unsigned int)u << 16);
}

// ---------------------------------------------------------------------------
// Pack weights: out[n][k] = w[k][n&1023] for gate n>>10, bf16. 64x64 LDS transpose.
__global__ __launch_bounds__(256) void pack_wT(
    const float* __restrict__ w0, const float* __restrict__ w1,
    const float* __restrict__ w2, const float* __restrict__ w3,
    const float* __restrict__ w4, const float* __restrict__ w5,
    const float* __restrict__ w6, const float* __restrict__ w7,
    unsigned short* __restrict__ wiT, unsigned short* __restrict__ whT)
{
    __shared__ float tl[64][65];
    int bid = blockIdx.x;
    int mi = bid >> 8;          // 0..3 = Wi gates i,f,g,o; 4..7 = Wh
    int tile = bid & 255;
    int tk = tile >> 4, tj = tile & 15;
    const float* w;
    int gate = mi & 3;
    if (mi < 4) w = (gate == 0) ? w0 : (gate == 1) ? w1 : (gate == 2) ? w2 : w3;
    else        w = (gate == 0) ? w4 : (gate == 1) ? w5 : (gate == 2) ? w6 : w7;
    unsigned short* out = (mi < 4) ? wiT : whT;
    int tx = threadIdx.x & 63, ty = threadIdx.x >> 6;
    #pragma unroll
    for (int i = 0; i < 16; i++) {
        int k = i * 4 + ty;
        tl[k][tx] = w[(long)(tk * 64 + k) * 1024 + tj * 64 + tx];
    }
    __syncthreads();
    #pragma unroll
    for (int i = 0; i < 16; i++) {
        int j = i * 4 + ty;
        out[(long)(gate * 1024 + tj * 64 + j) * 1024 + tk * 64 + tx] = f2bf(tl[tx][j]);
    }
}

// ---------------------------------------------------------------------------
__global__ __launch_bounds__(256) void pack_misc(
    const float* __restrict__ bi0, const float* __restrict__ bh0,
    const float* __restrict__ bi1, const float* __restrict__ bh1,
    const float* __restrict__ bi2, const float* __restrict__ bh2,
    const float* __restrict__ bi3, const float* __restrict__ bh3,
    float* __restrict__ bias, unsigned int* __restrict__ hbuf_u,
    unsigned int* __restrict__ flags)
{
    int idx = blockIdx.x * 256 + threadIdx.x;   // grid 256x256 = 65536
    hbuf_u[idx] = 0u;                            // 262144 B: both parities zeroed
    if (idx < 4096) {
        int g = idx >> 10, j = idx & 1023;
        const float* bi = (g == 0) ? bi0 : (g == 1) ? bi1 : (g == 2) ? bi2 : bi3;
        const float* bh = (g == 0) ? bh0 : (g == 1) ? bh1 : (g == 2) ? bh2 : bh3;
        bias[idx] = bi[j] + bh[j];
    }
    if (idx < 256) flags[idx] = 0u;              // 4 groups x 64 WG epoch flags
}

// ---------------------------------------------------------------------------
__global__ __launch_bounds__(256) void x2bf(const float* __restrict__ x,
                                            unsigned short* __restrict__ xbf)
{
    long i = ((long)blockIdx.x * 256 + threadIdx.x) * 8;   // grid 16384
    float4 a = *(const float4*)&x[i];
    float4 b = *(const float4*)&x[i + 4];
    uint4 v;
    v.x = (unsigned int)f2bf(a.x) | ((unsigned int)f2bf(a.y) << 16);
    v.y = (unsigned int)f2bf(a.z) | ((unsigned int)f2bf(a.w) << 16);
    v.z = (unsigned int)f2bf(b.x) | ((unsigned int)f2bf(b.y) << 16);
    v.w = (unsigned int)f2bf(b.z) | ((unsigned int)f2bf(b.w) << 16);
    *(uint4*)&xbf[i] = v;
}

// ---------------------------------------------------------------------------
// x_proj GEMM: xbf[32768][1024] @ Wi[1024][4096] -> xp[m][h][gate] bf16.
// 128x128 tile, BK=64, global_load_lds width=16 staging, XOR-swizzled chunks.
__global__ __launch_bounds__(256, 2) void gemm_xproj(
    const unsigned short* __restrict__ xbf, const unsigned short* __restrict__ wiT,
    unsigned short* __restrict__ xp)
{
    __shared__ unsigned short sA[128 * 64];   // [row][8 chunks of 8 bf16], swizzled
    __shared__ unsigned short sB[128 * 64];
    int bid = blockIdx.x;
    int mt = bid >> 5, nt = bid & 31;
    long m0 = (long)mt * 128;
    int n0 = nt * 128;
    int tid = threadIdx.x;
    int lane = tid & 63, wv = tid >> 6;
    int quad = lane >> 4, l15 = lane & 15;
    int wm = wv & 1, wn = wv >> 1;

    f32x4 acc[4][4];
    #pragma unroll
    for (int a = 0; a < 4; a++)
        #pragma unroll
        for (int b = 0; b < 4; b++)
            acc[a][b] = (f32x4){0.f, 0.f, 0.f, 0.f};

    for (int kb = 0; kb < 16; kb++) {
        int k0 = kb * 64;
        #pragma unroll
        for (int j = 0; j < 4; j++) {
            int Lb = wv * 256 + j * 64;                 // wave-uniform lds base chunk
            int row = (Lb >> 3) + (lane >> 3);
            int csrc = (lane & 7) ^ ((lane >> 3) & 7);
            const unsigned short* gA = xbf + (m0 + row) * 1024 + k0 + csrc * 8;
            __builtin_amdgcn_global_load_lds(
                (const __attribute__((address_space(1))) unsigned int*)gA,
                (__attribute__((address_space(3))) unsigned int*)&sA[Lb * 8],
                16, 0, 0);
            const unsigned short* gB = wiT + (long)(n0 + row) * 1024 + k0 + csrc * 8;
            __builtin_amdgcn_global_load_lds(
                (const __attribute__((address_space(1))) unsigned int*)gB,
                (__attribute__((address_space(3))) unsigned int*)&sB[Lb * 8],
                16, 0, 0);
        }
        __syncthreads();
        #pragma unroll
        for (int ks = 0; ks < 2; ks++) {
            bf16x8 af[4], bfr[4];
            #pragma unroll
            for (int mi2 = 0; mi2 < 4; mi2++) {
                int r = wm * 64 + mi2 * 16 + l15;
                af[mi2] = *(const bf16x8*)&sA[r * 64 + ((ks * 4 + quad) ^ (r & 7)) * 8];
            }
            #pragma unroll
            for (int ni = 0; ni < 4; ni++) {
                int r = wn * 64 + ni * 16 + l15;
                bfr[ni] = *(const bf16x8*)&sB[r * 64 + ((ks * 4 + quad) ^ (r & 7)) * 8];
            }
            #pragma unroll
            for (int mi2 = 0; mi2 < 4; mi2++)
                #pragma unroll
                for (int ni = 0; ni < 4; ni++)
                    acc[mi2][ni] = __builtin_amdgcn_mfma_f32_16x16x32_bf16(
                        af[mi2], bfr[ni], acc[mi2][ni], 0, 0, 0);
        }
        __syncthreads();
    }
    // epilogue: C rows = quad*4+r, cols = l15; gate-interleave scatter xp[m][h][gate]
    #pragma unroll
    for (int mi2 = 0; mi2 < 4; mi2++)
        #pragma unroll
        for (int ni = 0; ni < 4; ni++)
            #pragma unroll
            for (int r = 0; r < 4; r++) {
                long row = m0 + wm * 64 + mi2 * 16 + quad * 4 + r;
                int col = n0 + wn * 64 + ni * 16 + l15;
                int h = col & 1023, gate = col >> 10;
                xp[row * 4096 + h * 4 + gate] = f2bf(acc[mi2][ni][r]);
            }
}

// ---------------------------------------------------------------------------
// Persistent LSTM scan. 256 blocks x 256 threads.
// group g = bid/64 (batch rows 16g..16g+15), slice s = bid%64 (h cols 16s..16s+15).
// R4 flag barrier + split-half pipeline:
//   poll flags[0..31] -> issue stage half1 -> poll flags[32..63] (absorbs half1 RTT)
//   -> issue stage half2 -> vmcnt(4) -> LDS write half1 -> s_barrier(lgkm only)
//   -> MFMA kk0..15 (half2 in flight) -> vmcnt(0) -> LDS write half2 -> sync
//   -> MFMA kk16..31 -> xch -> cell -> publish(WT store) -> sync(drain) -> flag.
__global__ __launch_bounds__(256, 2) void lstm_scan(
    const unsigned short* __restrict__ xp, const unsigned short* __restrict__ whT,
    const float* __restrict__ bias, unsigned short* __restrict__ hbuf,
    unsigned int* __restrict__ flags, float* __restrict__ out)
{
    __shared__ unsigned short hl[16 * 1032];  // h tile [16][1024] bf16, stride 1032
    __shared__ float xch[4][16][16];          // gate exchange

    int bid = blockIdx.x;
    int g = bid >> 6, s = bid & 63;
    int tid = threadIdx.x;
    int lane = tid & 63, wv = tid >> 6;
    int quad = lane >> 4, l15 = lane & 15;

    // preload Wh fragments: B[k=kk*32+quad*8+j][n=l15] from WhT row (gate,col)
    bf16x8 bfrag[32];
    {
        const unsigned short* bp = whT + (long)(wv * 1024 + s * 16 + l15) * 1024 + quad * 8;
        #pragma unroll
        for (int kk = 0; kk < 32; kk++)
            bfrag[kk] = *(const bf16x8*)(bp + kk * 32);
    }

    int row = tid >> 4, col = tid & 15;       // elementwise ownership
    float b4[4];
    #pragma unroll
    for (int gg = 0; gg < 4; gg++) b4[gg] = bias[gg * 1024 + s * 16 + col];

    float c = 0.f;
    const unsigned int* fb = flags + g * 64;
    unsigned int* myflag = flags + g * 64 + s;
    const char* hb0 = (const char*)(hbuf + g * 16 * 1024);
    const char* hb1 = (const char*)(hbuf + 4 * 16 * 1024 + g * 16 * 1024);
    unsigned short* hw0 = hbuf + g * 16 * 1024;
    unsigned short* hw1 = hbuf + 4 * 16 * 1024 + g * 16 * 1024;

    const unsigned int* f1p = fb + (lane & 31);        // half1 flags 0..31
    const unsigned int* f2p = fb + 32 + (lane & 31);   // half2 flags 32..63

    for (int t = 0; t < 512; t++) {
        // x_proj prefetch: one 8B cached load = all 4 gates (hidden behind polls)
        const unsigned short* xr = xp + ((long)(g * 16 + row) * 512 + t) * 4096
                                      + (s * 16 + col) * 4;
        uint2 xg = *(const uint2*)xr;

        const char* hsrc = (t & 1) ? hb1 : hb0;
        unsigned int tt = (unsigned int)t;

        // poll half1 producer flags (slices 0..31 = h cols 0..511)
        if (t > 0) {
            while (true) {
                unsigned int f;
                asm volatile("global_load_dword %0, %1, off sc0 sc1\n\ts_waitcnt vmcnt(0)"
                             : "=v"(f) : "v"(f1p) : "memory");
                if (__all((int)(f >= tt))) break;
                __builtin_amdgcn_s_sleep(1);
            }
        }
        // issue stage half1 (cols 0..511): 4 x 16B per thread, no wait
        uint4v hv[8];
        #pragma unroll
        for (int i = 0; i < 4; i++) {
            int ch = tid + i * 256;                 // 1024 chunks
            int r2 = ch >> 6, off = ch & 63;
            const void* p = hsrc + r2 * 2048 + off * 16;
            asm volatile("global_load_dwordx4 %0, %1, off sc0 sc1"
                         : "=v"(hv[i]) : "v"(p) : "memory");
        }
        // poll half2 flags; its vmcnt(0) also absorbs half1 staging latency
        if (t > 0) {
            while (true) {
                unsigned int f;
                asm volatile("global_load_dword %0, %1, off sc0 sc1\n\ts_waitcnt vmcnt(0)"
                             : "=v"(f) : "v"(f2p) : "memory");
                if (__all((int)(f >= tt))) break;
                __builtin_amdgcn_s_sleep(1);
            }
        }
        // issue stage half2 (cols 512..1023)
        #pragma unroll
        for (int i = 0; i < 4; i++) {
            int ch = tid + i * 256;
            int r2 = ch >> 6, off = ch & 63;
            const void* p = hsrc + r2 * 2048 + 1024 + off * 16;
            asm volatile("global_load_dwordx4 %0, %1, off sc0 sc1"
                         : "=v"(hv[4 + i]) : "v"(p) : "memory");
        }
        // wait half1 only (half2 + nothing else outstanding: xp drained by polls;
        // at t==0 vmcnt(4) drains xp+half1, leaving half2's 4)
        asm volatile("s_waitcnt vmcnt(4)" ::: "memory");
        #pragma unroll
        for (int i = 0; i < 4; i++) {
            int ch = tid + i * 256;
            int r2 = ch >> 6, off = ch & 63;
            *(uint4v*)&hl[r2 * 1032 + off * 8] = hv[i];
        }
        // LDS-only barrier (raw s_barrier; avoids compiler's vmcnt(0) drain that
        // would wait for half2 and kill the overlap)
        asm volatile("s_waitcnt lgkmcnt(0)\n\ts_barrier" ::: "memory");

        // MFMA on half1 (kk 0..15) while half2 staging is in flight
        f32x4 acc = {0.f, 0.f, 0.f, 0.f};
        #pragma unroll
        for (int kk = 0; kk < 16; kk++) {
            bf16x8 af = *(const bf16x8*)&hl[l15 * 1032 + kk * 32 + quad * 8];
            acc = __builtin_amdgcn_mfma_f32_16x16x32_bf16(af, bfrag[kk], acc, 0, 0, 0);
        }

        // drain half2, write to LDS, full barrier, MFMA kk 16..31
        asm volatile("s_waitcnt vmcnt(0)" ::: "memory");
        #pragma unroll
        for (int i = 0; i < 4; i++) {
            int ch = tid + i * 256;
            int r2 = ch >> 6, off = ch & 63;
            *(uint4v*)&hl[r2 * 1032 + 512 + off * 8] = hv[4 + i];
        }
        asm volatile("s_waitcnt lgkmcnt(0)\n\ts_barrier" ::: "memory");
        #pragma unroll
        for (int kk = 16; kk < 32; kk++) {
            bf16x8 af = *(const bf16x8*)&hl[l15 * 1032 + kk * 32 + quad * 8];
            acc = __builtin_amdgcn_mfma_f32_16x16x32_bf16(af, bfrag[kk], acc, 0, 0, 0);
        }

        #pragma unroll
        for (int r = 0; r < 4; r++)
            xch[wv][quad * 4 + r][l15] = acc[r];
        __syncthreads();

        // elementwise LSTM cell
        float xpi = bf2f((unsigned short)(xg.x & 0xFFFF));
        float xpf = bf2f((unsigned short)(xg.x >> 16));
        float xpg = bf2f((unsigned short)(xg.y & 0xFFFF));
        float xpo = bf2f((unsigned short)(xg.y >> 16));
        float gi = xch[0][row][col] + xpi + b4[0];
        float gf = xch[1][row][col] + xpf + b4[1];
        float gg_ = xch[2][row][col] + xpg + b4[2];
        float go = xch[3][row][col] + xpo + b4[3];
        float iv = 1.f / (1.f + __expf(-gi));
        float fv = 1.f / (1.f + __expf(-gf));
        float gv = 1.f - 2.f / (__expf(2.f * gg_) + 1.f);   // tanh
        float ov = 1.f / (1.f + __expf(-go));
        c = c * fv + iv * gv;
        float h = ov * (1.f - 2.f / (__expf(2.f * c) + 1.f));

        if (t == 511) {
            out[(g * 16 + row) * 1024 + s * 16 + col] = h;
            out[65536 + (g * 16 + row) * 1024 + s * 16 + col] = c;
        } else {
            // publish h slice write-through (visible at MALL once retired)
            unsigned short* hdst = (t & 1) ? hw0 : hw1;
            __hip_atomic_store(&hdst[row * 1024 + s * 16 + col], f2bf(h),
                               __ATOMIC_RELAXED, __HIP_MEMORY_SCOPE_AGENT);
            // full __syncthreads: compiler drains vmcnt(0) before s_barrier, so
            // after it ALL this WG's h stores are at the coherence point.
            __syncthreads();
            if (tid == 0)
                __hip_atomic_store(myflag, tt + 1u,
                                   __ATOMIC_RELAXED, __HIP_MEMORY_SCOPE_AGENT);
        }
    }
}

// ---------------------------------------------------------------------------
extern "C" void kernel_launch(void* const* d_in, const int* in_sizes, int n_in,
                              void* d_out, int out_size, void* d_ws, size_t ws_size,
                              hipStream_t stream)
{
    const float* x    = (const float*)d_in[0];
    const float* w_ii = (const float*)d_in[1];
    const float* b_ii = (const float*)d_in[2];
    const float* w_hi = (const float*)d_in[3];
    const float* b_hi = (const float*)d_in[4];
    const float* w_if = (const float*)d_in[5];
    const float* b_if = (const float*)d_in[6];
    const float* w_hf = (const float*)d_in[7];
    const float* b_hf = (const float*)d_in[8];
    const float* w_ig = (const float*)d_in[9];
    const float* b_ig = (const float*)d_in[10];
    const float* w_hg = (const float*)d_in[11];
    const float* b_hg = (const float*)d_in[12];
    const float* w_io = (const float*)d_in[13];
    const float* b_io = (const float*)d_in[14];
    const float* w_ho = (const float*)d_in[15];
    const float* b_ho = (const float*)d_in[16];

    // Workspace layout. Total = 352,602,112 B.
    const size_t OFF_XPJ  = 0;                       // 268,435,456
    const size_t OFF_XBF  = 268435456;               //  67,108,864
    const size_t OFF_WIT  = 335544320;               //   8,388,608
    const size_t OFF_WHT  = 343932928;               //   8,388,608
    const size_t OFF_BIAS = 352321536;               //      16,384
    const size_t OFF_HBUF = 352337920;               //     262,144
    const size_t OFF_FLG  = 352600064;               //       2,048
    const size_t NEEDED   = 352602112;
    if (ws_size < NEEDED) return;

    char* ws = (char*)d_ws;
    unsigned short* xpj  = (unsigned short*)(ws + OFF_XPJ);
    unsigned short* xbf  = (unsigned short*)(ws + OFF_XBF);
    unsigned short* wiT  = (unsigned short*)(ws + OFF_WIT);
    unsigned short* whT  = (unsigned short*)(ws + OFF_WHT);
    float*          bias = (float*)(ws + OFF_BIAS);
    unsigned short* hbuf = (unsigned short*)(ws + OFF_HBUF);
    unsigned int*   flags = (unsigned int*)(ws + OFF_FLG);

    pack_wT<<<2048, 256, 0, stream>>>(w_ii, w_if, w_ig, w_io,
                                      w_hi, w_hf, w_hg, w_ho, wiT, whT);
    pack_misc<<<256, 256, 0, stream>>>(b_ii, b_hi, b_if, b_hf, b_ig, b_hg, b_io, b_ho,
                                       bias, (unsigned int*)hbuf, flags);
    x2bf<<<16384, 256, 0, stream>>>(x, xbf);
    gemm_xproj<<<8192, 256, 0, stream>>>(xbf, wiT, xpj);
    lstm_scan<<<256, 256, 0, stream>>>(xpj, whT, bias, hbuf, flags, (float*)d_out);
}